// Round 4
// baseline (89.152 us; speedup 1.0000x reference)
//
#include <hip/hip_runtime.h>
#include <hip/hip_bf16.h>

#define BN 4096
#define DD 128
#define NCLS 64
#define MARGIN_F 1.0f
#define NTRI32 8256      // 128*129/2 triangle tiles of 32x32
#define NSBLK 2064       // NTRI32 / 4 waves per block

typedef __attribute__((ext_vector_type(8))) short bf16x8;
typedef __attribute__((ext_vector_type(4))) float f32x4;

__device__ __forceinline__ unsigned short f2bf(float f) {
    __hip_bfloat16 h = __float2bfloat16(f);
    return *reinterpret_cast<unsigned short*>(&h);
}

// K1: fp32->bf16, row norms, zero neg, class histogram (fused).
// 512 blocks x 256 thr; each wave handles 2 rows (32 lanes/row, float4/lane).
__global__ __launch_bounds__(256) void prep_kernel(
    const float* __restrict__ score,
    const int* __restrict__ tgt,
    unsigned short* __restrict__ sbf,
    float* __restrict__ mag,
    float* __restrict__ neg,
    int* __restrict__ bins)
{
    const int tid = threadIdx.x;
    const int w = tid >> 6, lane = tid & 63;
    const int row = blockIdx.x * 8 + w * 2 + (lane >> 5);
    const int l32 = lane & 31;
    float4 v = *reinterpret_cast<const float4*>(score + (size_t)row * DD + l32 * 4);
    ushort4 u;
    u.x = f2bf(v.x); u.y = f2bf(v.y); u.z = f2bf(v.z); u.w = f2bf(v.w);
    *reinterpret_cast<ushort4*>(sbf + (size_t)row * DD + l32 * 4) = u;
    float s = v.x * v.x + v.y * v.y + v.z * v.z + v.w * v.w;
    #pragma unroll
    for (int o = 16; o > 0; o >>= 1) s += __shfl_xor(s, o);
    if (l32 == 0) {
        mag[row] = s;
        neg[row] = 0.0f;
        atomicAdd(&bins[tgt[row]], 1);
    }
}

// K2: neg_sum over symmetric triangle, 32x32 wave-tiles, 4 waves/block.
// Block NSBLK is a special block doing the class-sort scan+scatter concurrently.
__global__ __launch_bounds__(256) void negsum_kernel(
    const unsigned short* __restrict__ sbf,
    const float* __restrict__ mag,
    const int* __restrict__ tgt,
    float* __restrict__ neg,
    const int* __restrict__ bins,
    int* __restrict__ cursor,
    int* __restrict__ perm)
{
    const int bid = blockIdx.x;
    const int tid = threadIdx.x;

    if (bid == NSBLK) {
        // class-sorted permutation: exclusive scan of bins, then scatter
        __shared__ int soff[NCLS];
        if (tid < NCLS) {
            int v = bins[tid];
            int inc = v;
            #pragma unroll
            for (int o = 1; o < 64; o <<= 1) {
                int uu = __shfl_up(inc, o);
                if (tid >= o) inc += uu;
            }
            soff[tid] = inc - v;
        }
        __syncthreads();
        for (int i = tid; i < BN; i += 256) {
            const int c = tgt[i];
            const int pos = soff[c] + atomicAdd(&cursor[c], 1);
            perm[pos] = i;
        }
        return;
    }

    const int wid = tid >> 6;
    const int lane = tid & 63;
    const int idx = bid * 4 + wid;   // < 8256
    // decode triangle tile (bi <= bj) in a 128x128 tile grid
    int bi = (int)((257.0f - sqrtf(66049.0f - 8.0f * (float)idx)) * 0.5f);
    bi = max(0, min(bi, 127));
    while (bi * (257 - bi) / 2 > idx) --bi;
    while ((bi + 1) * (256 - bi) / 2 <= idx) ++bi;
    const int bj = bi + (idx - bi * (257 - bi) / 2);
    const bool diag = (bi == bj);
    const int i0 = bi * 32, j0 = bj * 32;
    const int lhi = lane >> 4, llo = lane & 15;

    f32x4 acc[2][2] = {};
    #pragma unroll
    for (int kk = 0; kk < 4; ++kk) {
        const int koff = kk * 32 + lhi * 8;
        bf16x8 a[2], b[2];
        #pragma unroll
        for (int m = 0; m < 2; ++m)
            a[m] = *reinterpret_cast<const bf16x8*>(sbf + (size_t)(i0 + m * 16 + llo) * DD + koff);
        #pragma unroll
        for (int n = 0; n < 2; ++n)
            b[n] = *reinterpret_cast<const bf16x8*>(sbf + (size_t)(j0 + n * 16 + llo) * DD + koff);
        #pragma unroll
        for (int m = 0; m < 2; ++m)
            #pragma unroll
            for (int n = 0; n < 2; ++n)
                acc[m][n] = __builtin_amdgcn_mfma_f32_16x16x32_bf16(a[m], b[n], acc[m][n], 0, 0, 0);
    }

    float magj[2]; int tj[2];
    #pragma unroll
    for (int n = 0; n < 2; ++n) {
        const int j = j0 + n * 16 + llo;
        magj[n] = mag[j];
        tj[n] = tgt[j];
    }

    float cs[2] = {0.0f, 0.0f};
    // C/D layout: col = lane&15 (j), row = (lane>>4)*4 + r (i)
    #pragma unroll
    for (int m = 0; m < 2; ++m) {
        const int ibase = i0 + m * 16 + lhi * 4;
        f32x4 magi = *reinterpret_cast<const f32x4*>(mag + ibase);
        int4 ti4 = *reinterpret_cast<const int4*>(tgt + ibase);
        const int* tip = &ti4.x;
        #pragma unroll
        for (int r = 0; r < 4; ++r) {
            const int ti = tip[r];
            float s = 0.0f;
            #pragma unroll
            for (int n = 0; n < 2; ++n) {
                float d2 = magi[r] + magj[n] - 2.0f * acc[m][n][r];
                d2 = fmaxf(d2, 0.0f);
                float dist = sqrtf(d2);
                float v = (ti != tj[n]) ? __expf(MARGIN_F - dist) : 0.0f;
                s += v;
                cs[n] += v;
            }
            #pragma unroll
            for (int o = 1; o < 16; o <<= 1) s += __shfl_xor(s, o);
            if (llo == 0) atomicAdd(&neg[ibase + r], s);
        }
    }
    if (!diag) {
        #pragma unroll
        for (int n = 0; n < 2; ++n) {
            cs[n] += __shfl_xor(cs[n], 16);
            cs[n] += __shfl_xor(cs[n], 32);
        }
        if (lhi == 0) {
            #pragma unroll
            for (int n = 0; n < 2; ++n)
                atomicAdd(&neg[j0 + n * 16 + llo], cs[n]);
        }
    }
}

// K3: per-class loss (gathered MFMA tile) + tail-block finalize.
__global__ __launch_bounds__(256) void loss_kernel(
    const unsigned short* __restrict__ sbf,
    const float* __restrict__ mag,
    const float* __restrict__ neg,
    const int* __restrict__ bins,
    const int* __restrict__ perm,
    float2* __restrict__ part,
    int* __restrict__ tail,
    float* __restrict__ out)
{
    const int c = blockIdx.x;
    const int tid = threadIdx.x;
    const int wid = tid >> 6, lane = tid & 63;

    __shared__ int sbase, scnt;
    if (tid < 64) {
        int v = (lane < c) ? bins[lane] : 0;
        #pragma unroll
        for (int o = 32; o > 0; o >>= 1) v += __shfl_xor(v, o);
        if (lane == 0) { sbase = v; scnt = bins[c]; }
    }
    __syncthreads();
    const int base = sbase, n_c = scnt;

    const int wr = wid >> 1, wc = wid & 1;
    const int p0 = wr * 64, q0 = wc * 64;
    const int lhi = lane >> 4, llo = lane & 15;

    float lsum = 0.0f, lcnt = 0.0f;
    const bool active = (n_c > 0) && (wc >= wr) && (p0 < n_c) && (q0 < n_c);
    if (active) {
        int opA[4], opB[4];
        #pragma unroll
        for (int m = 0; m < 4; ++m) {
            const int p = p0 + m * 16 + llo;
            opA[m] = perm[base + min(p, n_c - 1)];
        }
        #pragma unroll
        for (int n = 0; n < 4; ++n) {
            const int q = q0 + n * 16 + llo;
            opB[n] = perm[base + min(q, n_c - 1)];
        }
        f32x4 acc[4][4] = {};
        #pragma unroll
        for (int kk = 0; kk < 4; ++kk) {
            const int koff = kk * 32 + lhi * 8;
            bf16x8 a[4], b[4];
            #pragma unroll
            for (int m = 0; m < 4; ++m)
                a[m] = *reinterpret_cast<const bf16x8*>(sbf + (size_t)opA[m] * DD + koff);
            #pragma unroll
            for (int n = 0; n < 4; ++n)
                b[n] = *reinterpret_cast<const bf16x8*>(sbf + (size_t)opB[n] * DD + koff);
            #pragma unroll
            for (int m = 0; m < 4; ++m)
                #pragma unroll
                for (int n = 0; n < 4; ++n)
                    acc[m][n] = __builtin_amdgcn_mfma_f32_16x16x32_bf16(a[m], b[n], acc[m][n], 0, 0, 0);
        }

        float magjv[4], nsj[4]; int qv[4];
        #pragma unroll
        for (int n = 0; n < 4; ++n) {
            qv[n] = q0 + n * 16 + llo;
            magjv[n] = mag[opB[n]];
            nsj[n] = neg[opB[n]];
        }

        #pragma unroll
        for (int m = 0; m < 4; ++m) {
            #pragma unroll
            for (int r = 0; r < 4; ++r) {
                const int p = p0 + m * 16 + lhi * 4 + r;
                const bool pv = (p < n_c);
                const int io = perm[base + min(p, n_c - 1)];
                const float magiv = mag[io];
                const float nsi = neg[io];
                #pragma unroll
                for (int n = 0; n < 4; ++n) {
                    if (pv && qv[n] > p && qv[n] < n_c) {
                        float d2 = magiv + magjv[n] - 2.0f * acc[m][n][r];
                        d2 = fmaxf(d2, 0.0f);
                        float dist = sqrtf(d2);
                        float ln = __logf(nsi + nsj[n]);
                        float uu = fmaxf(ln + dist, 0.0f);
                        lsum += uu * uu;
                        lcnt += 1.0f;
                    }
                }
            }
        }
    }

    #pragma unroll
    for (int o = 32; o > 0; o >>= 1) {
        lsum += __shfl_xor(lsum, o);
        lcnt += __shfl_xor(lcnt, o);
    }
    __shared__ float2 wpart[4];
    __shared__ int dlast;
    if (lane == 0) wpart[wid] = make_float2(lsum, lcnt);
    __syncthreads();
    if (tid == 0) {
        float s = 0.0f, cc = 0.0f;
        #pragma unroll
        for (int w = 0; w < 4; ++w) { s += wpart[w].x; cc += wpart[w].y; }
        part[c] = make_float2(s, cc);
        __threadfence();
        dlast = (atomicAdd(tail, 1) == NCLS - 1) ? 1 : 0;
    }
    __syncthreads();
    if (dlast && tid < 64) {
        __threadfence();
        float2 p = part[lane];
        float s = p.x, cc = p.y;
        #pragma unroll
        for (int o = 32; o > 0; o >>= 1) {
            s += __shfl_xor(s, o);
            cc += __shfl_xor(cc, o);
        }
        if (lane == 0) out[0] = s / (2.0f * fmaxf(cc, 1.0f));
    }
}

extern "C" void kernel_launch(void* const* d_in, const int* in_sizes, int n_in,
                              void* d_out, int out_size, void* d_ws, size_t ws_size,
                              hipStream_t stream) {
    const float* score = (const float*)d_in[0];
    const int* tgt = (const int*)d_in[1];
    float* out = (float*)d_out;

    char* ws = (char*)d_ws;
    unsigned short* sbf = (unsigned short*)ws;               // 1 MB
    float* mag = (float*)(ws + (size_t)BN * DD * 2);         // 16 KB
    float* neg = mag + BN;                                   // 16 KB
    int* perm = (int*)(neg + BN);                            // 16 KB
    int* bins = perm + BN;                                   // 64 ints
    int* cursor = bins + NCLS;                               // 64 ints
    int* tail = cursor + NCLS;                               // 1 int (+1 pad)
    float2* part = (float2*)(tail + 2);                      // 64 float2, 8B-aligned

    // zero bins + cursor + tail (130 ints)
    hipMemsetAsync(bins, 0, (2 * NCLS + 2) * sizeof(int), stream);

    prep_kernel<<<512, 256, 0, stream>>>(score, tgt, sbf, mag, neg, bins);
    negsum_kernel<<<NSBLK + 1, 256, 0, stream>>>(sbf, mag, tgt, neg, bins, cursor, perm);
    loss_kernel<<<NCLS, 256, 0, stream>>>(sbf, mag, neg, bins, perm, part, tail, out);
}

// Round 5
// 81.928 us; speedup vs baseline: 1.0882x; 1.0882x over previous
//
#include <hip/hip_runtime.h>
#include <hip/hip_bf16.h>

#define BN 4096
#define DD 128
#define NCLS 64
#define MARGIN_F 1.0f
#define NSQ 1024        // 32x32 grid of 128x128 tiles (full square)

typedef __attribute__((ext_vector_type(8))) short bf16x8;
typedef __attribute__((ext_vector_type(4))) float f32x4;

__device__ __forceinline__ unsigned short f2bf(float f) {
    __hip_bfloat16 h = __float2bfloat16(f);
    return *reinterpret_cast<unsigned short*>(&h);
}

// async global->LDS, 16B per lane; lds dest = wave-uniform base + lane*16
__device__ __forceinline__ void gload_lds16(const void* g, void* l) {
    __builtin_amdgcn_global_load_lds(
        (const __attribute__((address_space(1))) unsigned int*)g,
        (__attribute__((address_space(3))) unsigned int*)l,
        16, 0, 0);
}

// K1: fp32->bf16, row norms, zero neg, class histogram (fused).
__global__ __launch_bounds__(256) void prep_kernel(
    const float* __restrict__ score,
    const int* __restrict__ tgt,
    unsigned short* __restrict__ sbf,
    float* __restrict__ mag,
    float* __restrict__ neg,
    int* __restrict__ bins)
{
    const int tid = threadIdx.x;
    const int w = tid >> 6, lane = tid & 63;
    const int row = blockIdx.x * 8 + w * 2 + (lane >> 5);
    const int l32 = lane & 31;
    float4 v = *reinterpret_cast<const float4*>(score + (size_t)row * DD + l32 * 4);
    ushort4 u;
    u.x = f2bf(v.x); u.y = f2bf(v.y); u.z = f2bf(v.z); u.w = f2bf(v.w);
    *reinterpret_cast<ushort4*>(sbf + (size_t)row * DD + l32 * 4) = u;
    float s = v.x * v.x + v.y * v.y + v.z * v.z + v.w * v.w;
    #pragma unroll
    for (int o = 16; o > 0; o >>= 1) s += __shfl_xor(s, o);
    if (l32 == 0) {
        mag[row] = s;
        neg[row] = 0.0f;
        atomicAdd(&bins[tgt[row]], 1);
    }
}

// K2: neg_sum, full 32x32 grid of 128x128 tiles, LDS-staged via global_load_lds.
// Block NSQ is a special block doing the class-sort scatter concurrently.
__global__ __launch_bounds__(256, 2) void negsum_kernel(
    const unsigned short* __restrict__ sbf,
    const float* __restrict__ mag,
    const int* __restrict__ tgt,
    float* __restrict__ neg,
    const int* __restrict__ bins,
    int* __restrict__ cursor,
    int* __restrict__ perm)
{
    const int bid = blockIdx.x;
    const int tid = threadIdx.x;
    const int wid = tid >> 6;
    const int lane = tid & 63;

    if (bid == NSQ) {
        // class-sorted permutation: per-wave redundant scan (no LDS), then scatter
        int v = (lane < NCLS) ? bins[lane] : 0;
        int inc = v;
        #pragma unroll
        for (int o = 1; o < 64; o <<= 1) {
            int uu = __shfl_up(inc, o);
            if (lane >= o) inc += uu;
        }
        const int exc = inc - v;   // lane t holds exclusive offset of class t
        for (int i = tid; i < BN; i += 256) {
            const int c = tgt[i];
            const int pos = __shfl(exc, c) + atomicAdd(&cursor[c], 1);
            perm[pos] = i;
        }
        return;
    }

    __shared__ __align__(16) unsigned short As[128 * 128];  // 32KB, xor-swizzled rows
    __shared__ __align__(16) unsigned short Bs[128 * 128];  // 32KB

    const int bi = bid & 31, bj = bid >> 5;
    const int i0 = bi * 128, j0 = bj * 128;

    // ---- stage A and B tiles (32KB each) ----
    // LDS slot byte L holds global tile byte  row*256 + ((L&255) ^ ((row&7)<<4)),
    // row = L>>8.  (involution: reader applies the same xor)
    {
        const char* Ag = (const char*)(sbf + (size_t)i0 * DD);
        const char* Bg = (const char*)(sbf + (size_t)j0 * DD);
        const int lb = lane * 16;
        #pragma unroll
        for (int c = 0; c < 8; ++c) {
            const int base = wid * 8192 + c * 1024;       // wave-uniform LDS byte base
            const int L = base + lb;
            const int row = L >> 8;
            const int off = (L & 255) ^ ((row & 7) << 4);
            gload_lds16(Ag + row * 256 + off, (char*)As + base);
            gload_lds16(Bg + row * 256 + off, (char*)Bs + base);
        }
    }
    __syncthreads();

    // ---- compute: wave (wr,wc) owns 64x64 of the 128x128 tile ----
    const int wr = wid >> 1, wc = wid & 1;
    const int lhi = lane >> 4, llo = lane & 15;

    f32x4 acc[4][4] = {};
    #pragma unroll
    for (int kk = 0; kk < 4; ++kk) {
        bf16x8 a[4], b[4];
        #pragma unroll
        for (int m = 0; m < 4; ++m) {
            const int row = wr * 64 + m * 16 + llo;
            const int bo = (kk * 64 + lhi * 16) ^ ((row & 7) << 4);
            a[m] = *reinterpret_cast<const bf16x8*>((const char*)As + row * 256 + bo);
        }
        #pragma unroll
        for (int n = 0; n < 4; ++n) {
            const int row = wc * 64 + n * 16 + llo;
            const int bo = (kk * 64 + lhi * 16) ^ ((row & 7) << 4);
            b[n] = *reinterpret_cast<const bf16x8*>((const char*)Bs + row * 256 + bo);
        }
        #pragma unroll
        for (int m = 0; m < 4; ++m)
            #pragma unroll
            for (int n = 0; n < 4; ++n)
                acc[m][n] = __builtin_amdgcn_mfma_f32_16x16x32_bf16(a[m], b[n], acc[m][n], 0, 0, 0);
    }

    // ---- epilogue (R2-proven): exp(margin-dist), row-reduce, atomic ----
    const int jw0 = j0 + wc * 64;
    float magj[4]; int tj[4];
    #pragma unroll
    for (int n = 0; n < 4; ++n) {
        const int j = jw0 + n * 16 + llo;
        magj[n] = mag[j];
        tj[n] = tgt[j];
    }

    // C/D layout: col = lane&15 (j), row = (lane>>4)*4 + r (i)
    #pragma unroll
    for (int m = 0; m < 4; ++m) {
        const int ibase = i0 + wr * 64 + m * 16 + lhi * 4;
        f32x4 magi = *reinterpret_cast<const f32x4*>(mag + ibase);
        int4 ti4 = *reinterpret_cast<const int4*>(tgt + ibase);
        const int* tip = &ti4.x;
        #pragma unroll
        for (int r = 0; r < 4; ++r) {
            const int ti = tip[r];
            float s = 0.0f;
            #pragma unroll
            for (int n = 0; n < 4; ++n) {
                float d2 = magi[r] + magj[n] - 2.0f * acc[m][n][r];
                d2 = fmaxf(d2, 0.0f);
                float dist = sqrtf(d2);
                s += (ti != tj[n]) ? __expf(MARGIN_F - dist) : 0.0f;
            }
            #pragma unroll
            for (int o = 1; o < 16; o <<= 1) s += __shfl_xor(s, o);
            if (llo == 0) atomicAdd(&neg[ibase + r], s);
        }
    }
}

// K3: per-class loss (gathered MFMA tile) + tail-block finalize.
__global__ __launch_bounds__(256) void loss_kernel(
    const unsigned short* __restrict__ sbf,
    const float* __restrict__ mag,
    const float* __restrict__ neg,
    const int* __restrict__ bins,
    const int* __restrict__ perm,
    float2* __restrict__ part,
    int* __restrict__ tail,
    float* __restrict__ out)
{
    const int c = blockIdx.x;
    const int tid = threadIdx.x;
    const int wid = tid >> 6, lane = tid & 63;

    __shared__ int sbase, scnt;
    if (tid < 64) {
        int v = (lane < c) ? bins[lane] : 0;
        #pragma unroll
        for (int o = 32; o > 0; o >>= 1) v += __shfl_xor(v, o);
        if (lane == 0) { sbase = v; scnt = bins[c]; }
    }
    __syncthreads();
    const int base = sbase, n_c = scnt;

    const int wr = wid >> 1, wc = wid & 1;
    const int p0 = wr * 64, q0 = wc * 64;
    const int lhi = lane >> 4, llo = lane & 15;

    float lsum = 0.0f, lcnt = 0.0f;
    const bool active = (n_c > 0) && (wc >= wr) && (p0 < n_c) && (q0 < n_c);
    if (active) {
        int opA[4], opB[4];
        #pragma unroll
        for (int m = 0; m < 4; ++m) {
            const int p = p0 + m * 16 + llo;
            opA[m] = perm[base + min(p, n_c - 1)];
        }
        #pragma unroll
        for (int n = 0; n < 4; ++n) {
            const int q = q0 + n * 16 + llo;
            opB[n] = perm[base + min(q, n_c - 1)];
        }
        f32x4 acc[4][4] = {};
        #pragma unroll
        for (int kk = 0; kk < 4; ++kk) {
            const int koff = kk * 32 + lhi * 8;
            bf16x8 a[4], b[4];
            #pragma unroll
            for (int m = 0; m < 4; ++m)
                a[m] = *reinterpret_cast<const bf16x8*>(sbf + (size_t)opA[m] * DD + koff);
            #pragma unroll
            for (int n = 0; n < 4; ++n)
                b[n] = *reinterpret_cast<const bf16x8*>(sbf + (size_t)opB[n] * DD + koff);
            #pragma unroll
            for (int m = 0; m < 4; ++m)
                #pragma unroll
                for (int n = 0; n < 4; ++n)
                    acc[m][n] = __builtin_amdgcn_mfma_f32_16x16x32_bf16(a[m], b[n], acc[m][n], 0, 0, 0);
        }

        float magjv[4], nsj[4]; int qv[4];
        #pragma unroll
        for (int n = 0; n < 4; ++n) {
            qv[n] = q0 + n * 16 + llo;
            magjv[n] = mag[opB[n]];
            nsj[n] = neg[opB[n]];
        }

        #pragma unroll
        for (int m = 0; m < 4; ++m) {
            #pragma unroll
            for (int r = 0; r < 4; ++r) {
                const int p = p0 + m * 16 + lhi * 4 + r;
                const bool pv = (p < n_c);
                const int io = perm[base + min(p, n_c - 1)];
                const float magiv = mag[io];
                const float nsi = neg[io];
                #pragma unroll
                for (int n = 0; n < 4; ++n) {
                    if (pv && qv[n] > p && qv[n] < n_c) {
                        float d2 = magiv + magjv[n] - 2.0f * acc[m][n][r];
                        d2 = fmaxf(d2, 0.0f);
                        float dist = sqrtf(d2);
                        float ln = __logf(nsi + nsj[n]);
                        float uu = fmaxf(ln + dist, 0.0f);
                        lsum += uu * uu;
                        lcnt += 1.0f;
                    }
                }
            }
        }
    }

    #pragma unroll
    for (int o = 32; o > 0; o >>= 1) {
        lsum += __shfl_xor(lsum, o);
        lcnt += __shfl_xor(lcnt, o);
    }
    __shared__ float2 wpart[4];
    __shared__ int dlast;
    if (lane == 0) wpart[wid] = make_float2(lsum, lcnt);
    __syncthreads();
    if (tid == 0) {
        float s = 0.0f, cc = 0.0f;
        #pragma unroll
        for (int w = 0; w < 4; ++w) { s += wpart[w].x; cc += wpart[w].y; }
        part[c] = make_float2(s, cc);
        __threadfence();
        dlast = (atomicAdd(tail, 1) == NCLS - 1) ? 1 : 0;
    }
    __syncthreads();
    if (dlast && tid < 64) {
        __threadfence();
        float2 p = part[lane];
        float s = p.x, cc = p.y;
        #pragma unroll
        for (int o = 32; o > 0; o >>= 1) {
            s += __shfl_xor(s, o);
            cc += __shfl_xor(cc, o);
        }
        if (lane == 0) out[0] = s / (2.0f * fmaxf(cc, 1.0f));
    }
}

extern "C" void kernel_launch(void* const* d_in, const int* in_sizes, int n_in,
                              void* d_out, int out_size, void* d_ws, size_t ws_size,
                              hipStream_t stream) {
    const float* score = (const float*)d_in[0];
    const int* tgt = (const int*)d_in[1];
    float* out = (float*)d_out;

    char* ws = (char*)d_ws;
    unsigned short* sbf = (unsigned short*)ws;               // 1 MB
    float* mag = (float*)(ws + (size_t)BN * DD * 2);         // 16 KB
    float* neg = mag + BN;                                   // 16 KB
    int* perm = (int*)(neg + BN);                            // 16 KB
    int* bins = perm + BN;                                   // 64 ints
    int* cursor = bins + NCLS;                               // 64 ints
    int* tail = cursor + NCLS;                               // 1 int (+1 pad)
    float2* part = (float2*)(tail + 2);                      // 64 float2, 8B-aligned

    // zero bins + cursor + tail
    hipMemsetAsync(bins, 0, (2 * NCLS + 2) * sizeof(int), stream);

    prep_kernel<<<512, 256, 0, stream>>>(score, tgt, sbf, mag, neg, bins);
    negsum_kernel<<<NSQ + 1, 256, 0, stream>>>(sbf, mag, tgt, neg, bins, cursor, perm);
    loss_kernel<<<NCLS, 256, 0, stream>>>(sbf, mag, neg, bins, perm, part, tail, out);
}